// Round 6
// baseline (547.622 us; speedup 1.0000x reference)
//
#include <hip/hip_runtime.h>
#include <hip/hip_bf16.h>

// ---------------------------------------------------------------------------
// Fused 3-layer GRU (B*N=16384 seqs, T=20, HS=128) for MI355X / gfx950.
// R19 = R13 (337 us proven) + ONE change: depth-2 within-phase software
// pipeline for the weight/B loads. Each gh/gi ks-step pre-loads the NEXT
// step's 3 weight frags (global, ~200cy L2) and 4 B frags (LDS) into fresh
// named registers while the current step's 12 MFMAs (~230 SIMD-cyc) run.
//   - live ranges span only one ks-step (R14/R15 lesson: loop-spanning
//     weight caches spill; rolling 1-step ranges do not).
//   - entirely within a phase (R16 lesson: cross-barrier prefetch neutral).
//   - LD stays 136 (R18 lesson: 140-half rows break 16B alignment of b128
//     LDS reads -> split ops; 16.4M "conflicts" are the b128 structural
//     floor, 256dw/32banks, not fixable by padding).
// Rationale: VGPR_Count=84 (acc=64) shows the compiler holds ~1 frag in
// flight; ~14 exposed ~150cy load groups/phase/wave matches the measured
// 35k cyc/phase vs ~26k pipe demand. Canaries: VGPR 120-150 (pipeline
// materialized), FETCH ~14 MB, WRITE ~28 MB (no spill).
// ---------------------------------------------------------------------------

typedef _Float16 half8 __attribute__((ext_vector_type(8)));
typedef _Float16 half4 __attribute__((ext_vector_type(4)));
typedef float floatx4 __attribute__((ext_vector_type(4)));

#define MFMA16(a, b, c) __builtin_amdgcn_mfma_f32_16x16x32_f16((a), (b), (c), 0, 0, 0)

static __device__ __forceinline__ float ldin(const void* p, long i, bool f32) {
    return f32 ? ((const float*)p)[i]
               : __bfloat162float(((const __hip_bfloat16*)p)[i]);
}

static __device__ __forceinline__ bool detect_f32(const void* peT, const void* x) {
    const __hip_bfloat16* a = (const __hip_bfloat16*)peT;
    const __hip_bfloat16* b = (const __hip_bfloat16*)x;
    bool weird = false;
    for (int i = 0; i < 20; i++) {
        float v = fabsf(__bfloat162float(a[i]));
        if (!(v == 0.0f || (v > 1e-8f && v < 1e8f))) weird = true;
    }
    for (int i = 0; i < 64; i++) {
        float v = fabsf(__bfloat162float(b[i]));
        if (!(v == 0.0f || (v > 1e-8f && v < 1e8f))) weird = true;
    }
    return weird;
}

static __device__ __forceinline__ float fsigm(float x) {
    x = fminf(fmaxf(x, -60.f), 60.f);
    float e = __builtin_amdgcn_exp2f(-1.442695041f * x);
    return __builtin_amdgcn_rcpf(1.0f + e);
}
static __device__ __forceinline__ float ftanh(float x) {
    x = fminf(fmaxf(x, -30.f), 30.f);
    float e = __builtin_amdgcn_exp2f(2.885390082f * x);  // exp(2x)
    return 1.0f - 2.0f * __builtin_amdgcn_rcpf(1.0f + e);
}

// ws fragment layout (each frag = 512 halfs = 64 lanes x 8): slot order
//   [0,288)   Whh   (3 layers x 96)   frag in layer: (ctile*3+g)*4+ks, ctile 0..7
//   [288,480) WihR  (2 layers x 96)   same formula
//   [480,528) Wih0  (48)              (ctile*3+g)*2+ks   (K=64)
//   [528,544) outW  (16)              otile*4+ks
__global__ __launch_bounds__(64) void prepack_kernel(
    const void* __restrict__ Whh,
    const void* __restrict__ WihR,
    const void* __restrict__ Wih0,
    const void* __restrict__ outW,
    const void* __restrict__ peT,
    const void* __restrict__ x,
    _Float16* __restrict__ ws)
{
    const bool f32 = detect_f32(peT, x);
    int fid  = blockIdx.x;
    int lane = threadIdx.x;
    int nlo = lane & 15, quad = lane >> 4;
    const void* src;
    long base;
    int row, k0, ldk;
    if (fid < 288) {
        int l = fid / 96, r = fid % 96;
        int ks = r & 3, q1 = r >> 2, g = q1 % 3, ctile = q1 / 3;
        row = g * 128 + ctile * 16 + nlo; k0 = ks * 32 + quad * 8; ldk = 128;
        src = Whh; base = (long)l * 384 * 128;
    } else if (fid < 480) {
        int f = fid - 288; int l = f / 96, r = f % 96;
        int ks = r & 3, q1 = r >> 2, g = q1 % 3, ctile = q1 / 3;
        row = g * 128 + ctile * 16 + nlo; k0 = ks * 32 + quad * 8; ldk = 128;
        src = WihR; base = (long)l * 384 * 128;
    } else if (fid < 528) {
        int r = fid - 480;
        int ks = r & 1, q1 = r >> 1, g = q1 % 3, ctile = q1 / 3;
        row = g * 128 + ctile * 16 + nlo; k0 = ks * 32 + quad * 8; ldk = 64;
        src = Wih0; base = 0;
    } else {
        int r = fid - 528; int ks = r & 3, ot = r >> 2;
        row = ot * 16 + nlo; k0 = ks * 32 + quad * 8; ldk = 128;
        src = outW; base = 0;
    }
    _Float16* d = ws + (long)fid * 512 + lane * 8;
#pragma unroll
    for (int j = 0; j < 8; j++)
        d[j] = (_Float16)ldin(src, base + (long)row * ldk + k0 + j, f32);
}

// 12 MFMAs of one ks-step: gates g0->acc[0], g1->acc[1], g2->acc[S2]
// (S2=3 for gh (Nh), S2=2 for gi (Ni))
#define MFMA12(W0, W1, W2, S2, Bq0, Bq1, Bq2, Bq3) \
    acc[0][0] = MFMA16((W0), Bq0, acc[0][0]); \
    acc[0][1] = MFMA16((W0), Bq1, acc[0][1]); \
    acc[0][2] = MFMA16((W0), Bq2, acc[0][2]); \
    acc[0][3] = MFMA16((W0), Bq3, acc[0][3]); \
    acc[1][0] = MFMA16((W1), Bq0, acc[1][0]); \
    acc[1][1] = MFMA16((W1), Bq1, acc[1][1]); \
    acc[1][2] = MFMA16((W1), Bq2, acc[1][2]); \
    acc[1][3] = MFMA16((W1), Bq3, acc[1][3]); \
    acc[S2][0] = MFMA16((W2), Bq0, acc[S2][0]); \
    acc[S2][1] = MFMA16((W2), Bq1, acc[S2][1]); \
    acc[S2][2] = MFMA16((W2), Bq2, acc[S2][2]); \
    acc[S2][3] = MFMA16((W2), Bq3, acc[S2][3]);

#define LDB4(D0, D1, D2, D3, BASE, STRIDE, KS) \
    D0 = *(const half8*)((BASE) + (0 * 16 + nlo) * (STRIDE) + (KS) * 32 + qk); \
    D1 = *(const half8*)((BASE) + (1 * 16 + nlo) * (STRIDE) + (KS) * 32 + qk); \
    D2 = *(const half8*)((BASE) + (2 * 16 + nlo) * (STRIDE) + (KS) * 32 + qk); \
    D3 = *(const half8*)((BASE) + (3 * 16 + nlo) * (STRIDE) + (KS) * 32 + qk);

__global__ __launch_bounds__(768, 3) void rnn_fused(
    const void* __restrict__ x,
    const void* __restrict__ peA,
    const void* __restrict__ peT,
    const void* __restrict__ embW,
    const void* __restrict__ embB,
    const void* __restrict__ bih,
    const void* __restrict__ bhh,
    const void* __restrict__ outB,
    const _Float16* __restrict__ ws,
    float* __restrict__ out)
{
    __shared__ __align__(16) _Float16 hA[3][2][64][136];
    __shared__ __align__(16) _Float16 eA[2][64][72];
    __shared__ float emb0[64], emb1[64], embb[64];
    __shared__ float biasS[1536];   // [l][R,Z,Ni,Nh][128]

    const bool f32 = detect_f32(peT, x);

    const int tid  = threadIdx.x;
    const int w    = tid >> 6;      // 0..11
    const int lane = tid & 63;
    const int nlo  = lane & 15;
    const int quad = lane >> 4;
    const int qk   = quad * 8;
    const int m0   = blockIdx.x * 64;
    const int rot  = blockIdx.x & 3;          // ks-order rotation (slice skew)
    const int ctr  = (blockIdx.x >> 2) & 1;   // ctile-order rotation
    const _Float16* wsl = ws + lane * 8;      // lane-offset weight base

    for (int i = tid; i < 3 * 2 * 64 * 136; i += 768)
        (&hA[0][0][0][0])[i] = (_Float16)0.f;
    if (tid < 64) {
        emb0[tid] = ldin(embW, tid * 2 + 0, f32);
        emb1[tid] = ldin(embW, tid * 2 + 1, f32);
        embb[tid] = ldin(embB, tid, f32);
    }
    for (int idx = tid; idx < 1536; idx += 768) {
        int l = idx >> 9, r = idx & 511, g = r >> 7, c = r & 127;
        float v;
        if      (g == 0) v = ldin(bih, l * 384 + c, f32)       + ldin(bhh, l * 384 + c, f32);
        else if (g == 1) v = ldin(bih, l * 384 + 128 + c, f32) + ldin(bhh, l * 384 + 128 + c, f32);
        else if (g == 2) v = ldin(bih, l * 384 + 256 + c, f32);
        else             v = ldin(bhh, l * 384 + 256 + c, f32);
        biasS[idx] = v;
    }

    const int em = tid >> 2;          // embedding seq (layer-0 waves: tid<256)
    const int ej = (tid & 3) * 16;    // embedding col base
    const float peAg = ldin(peA, ((m0 + em) & 7), f32);

    __syncthreads();

#pragma unroll 1
    for (int s = 0; s < 23; s++) {
        const int l = w >> 2;           // 0..2
        const int W = w & 3;            // quarter: ctiles W*2, W*2+1
        const int t = s - 1 - l;
        if (t >= 0 && t < 20) {
            const int p = (t + 1) & 1;
            const int q = t & 1;
            const int tb = t & 1;

#pragma unroll
            for (int ct0 = 0; ct0 < 2; ct0++) {
                const int c8 = W * 2 + ((ct0 + ctr) & 1);   // ctile 0..7
                const int c4 = c8 * 16 + quad * 4;

                floatx4 acc[4][4];                  // [R,Z,Ni,Nh][rt] - 64 regs
#pragma unroll
                for (int g = 0; g < 4; g++) {
                    floatx4 b = *(const floatx4*)&biasS[(l * 4 + g) * 128 + c4];
#pragma unroll
                    for (int rt = 0; rt < 4; rt++) acc[g][rt] = b;
                }

                // ---- gh section: h(t-1) @ Whh^T, depth-2 pipelined ----
                {
                    const _Float16* fb = wsl + (long)(l * 96 + c8 * 12) * 512;
                    const _Float16* bb = &hA[l][p][0][0];
                    const int k0 = rot;
                    half8 Wa0 = *(const half8*)(fb + (long)(0 * 4 + k0) * 512);
                    half8 Wa1 = *(const half8*)(fb + (long)(1 * 4 + k0) * 512);
                    half8 Wa2 = *(const half8*)(fb + (long)(2 * 4 + k0) * 512);
                    half8 Ba0, Ba1, Ba2, Ba3;
                    LDB4(Ba0, Ba1, Ba2, Ba3, bb, 136, k0)
#pragma unroll
                    for (int i = 0; i < 4; i++) {
                        half8 Wb0, Wb1, Wb2, Bb0, Bb1, Bb2, Bb3;
                        if (i < 3) {
                            const int nk = (rot + i + 1) & 3;
                            Wb0 = *(const half8*)(fb + (long)(0 * 4 + nk) * 512);
                            Wb1 = *(const half8*)(fb + (long)(1 * 4 + nk) * 512);
                            Wb2 = *(const half8*)(fb + (long)(2 * 4 + nk) * 512);
                            LDB4(Bb0, Bb1, Bb2, Bb3, bb, 136, nk)
                        }
                        MFMA12(Wa0, Wa1, Wa2, 3, Ba0, Ba1, Ba2, Ba3)
                        if (i < 3) {
                            Wa0 = Wb0; Wa1 = Wb1; Wa2 = Wb2;
                            Ba0 = Bb0; Ba1 = Bb1; Ba2 = Bb2; Ba3 = Bb3;
                        }
                    }
                }

                // ---- gi section: input(t) @ Wih^T, depth-2 pipelined ----
                if (l == 0) {
                    const _Float16* fb = wsl + (long)(480 + c8 * 6) * 512;
                    const _Float16* bb = &eA[tb][0][0];
                    const int k0 = rot & 1;
                    half8 Wa0 = *(const half8*)(fb + (long)(0 * 2 + k0) * 512);
                    half8 Wa1 = *(const half8*)(fb + (long)(1 * 2 + k0) * 512);
                    half8 Wa2 = *(const half8*)(fb + (long)(2 * 2 + k0) * 512);
                    half8 Ba0, Ba1, Ba2, Ba3;
                    LDB4(Ba0, Ba1, Ba2, Ba3, bb, 72, k0)
#pragma unroll
                    for (int i = 0; i < 2; i++) {
                        half8 Wb0, Wb1, Wb2, Bb0, Bb1, Bb2, Bb3;
                        if (i < 1) {
                            const int nk = k0 ^ 1;
                            Wb0 = *(const half8*)(fb + (long)(0 * 2 + nk) * 512);
                            Wb1 = *(const half8*)(fb + (long)(1 * 2 + nk) * 512);
                            Wb2 = *(const half8*)(fb + (long)(2 * 2 + nk) * 512);
                            LDB4(Bb0, Bb1, Bb2, Bb3, bb, 72, nk)
                        }
                        MFMA12(Wa0, Wa1, Wa2, 2, Ba0, Ba1, Ba2, Ba3)
                        if (i < 1) {
                            Wa0 = Wb0; Wa1 = Wb1; Wa2 = Wb2;
                            Ba0 = Bb0; Ba1 = Bb1; Ba2 = Bb2; Ba3 = Bb3;
                        }
                    }
                } else {
                    const _Float16* fb = wsl + (long)(288 + (l - 1) * 96 + c8 * 12) * 512;
                    const _Float16* bb = &hA[l - 1][tb][0][0];
                    const int k0 = rot;
                    half8 Wa0 = *(const half8*)(fb + (long)(0 * 4 + k0) * 512);
                    half8 Wa1 = *(const half8*)(fb + (long)(1 * 4 + k0) * 512);
                    half8 Wa2 = *(const half8*)(fb + (long)(2 * 4 + k0) * 512);
                    half8 Ba0, Ba1, Ba2, Ba3;
                    LDB4(Ba0, Ba1, Ba2, Ba3, bb, 136, k0)
#pragma unroll
                    for (int i = 0; i < 4; i++) {
                        half8 Wb0, Wb1, Wb2, Bb0, Bb1, Bb2, Bb3;
                        if (i < 3) {
                            const int nk = (rot + i + 1) & 3;
                            Wb0 = *(const half8*)(fb + (long)(0 * 4 + nk) * 512);
                            Wb1 = *(const half8*)(fb + (long)(1 * 4 + nk) * 512);
                            Wb2 = *(const half8*)(fb + (long)(2 * 4 + nk) * 512);
                            LDB4(Bb0, Bb1, Bb2, Bb3, bb, 136, nk)
                        }
                        MFMA12(Wa0, Wa1, Wa2, 2, Ba0, Ba1, Ba2, Ba3)
                        if (i < 3) {
                            Wa0 = Wb0; Wa1 = Wb1; Wa2 = Wb2;
                            Ba0 = Bb0; Ba1 = Bb1; Ba2 = Bb2; Ba3 = Bb3;
                        }
                    }
                }

                // nonlinearity + f16 writeback (b64) to buf q
#pragma unroll
                for (int rt = 0; rt < 4; rt++) {
                    half4 ho = *(const half4*)&hA[l][p][rt * 16 + nlo][c4];
                    half4 hn;
#pragma unroll
                    for (int rg = 0; rg < 4; rg++) {
                        float r = fsigm(acc[0][rt][rg]);
                        float z = fsigm(acc[1][rt][rg]);
                        float n = ftanh(acc[2][rt][rg] + r * acc[3][rt][rg]);
                        hn[rg] = (_Float16)(n + z * ((float)ho[rg] - n));
                    }
                    *(half4*)&hA[l][q][rt * 16 + nlo][c4] = hn;
                }
            }
        }
        // ---- embedding fused into layer-0 waves: e(t=s) -> eA[s&1] ----
        if (l == 0 && s < 20) {
            float x0 = ldin(x, ((long)(m0 + em) * 20 + s) * 2 + 0, f32);
            float x1 = ldin(x, ((long)(m0 + em) * 20 + s) * 2 + 1, f32);
            float pe = ldin(peT, s, f32) + peAg;
            float xp0 = x0 + pe, xp1 = x1 + pe;
#pragma unroll
            for (int jj = 0; jj < 16; jj++) {
                float e = fmaf(emb0[ej + jj], xp0, fmaf(emb1[ej + jj], xp1, embb[ej + jj]));
                eA[s & 1][em][ej + jj] = (_Float16)fmaxf(e, 0.f);
            }
        }
        __syncthreads();   // single barrier per phase
    }

    // ---- epilogue 1: out = h3(19) @ outW^T + out_b ; h3(19) in buf 1 ----
    if (w < 8) {
        const int otile = w & 3;
        const int rtb   = (w >> 2) * 2;
        half8 Ao[4];
#pragma unroll
        for (int ks = 0; ks < 4; ks++)
            Ao[ks] = *(const half8*)(wsl + (long)(528 + otile * 4 + ks) * 512);
        floatx4 ob;
#pragma unroll
        for (int rg = 0; rg < 4; rg++) ob[rg] = ldin(outB, otile * 16 + quad * 4 + rg, f32);
#pragma unroll
        for (int rr = 0; rr < 2; rr++) {
            const int rt = rtb + rr;
            floatx4 acc = ob;
#pragma unroll
            for (int ks = 0; ks < 4; ks++) {
                half8 b = *(const half8*)&hA[2][1][rt * 16 + nlo][ks * 32 + qk];
                acc = MFMA16(Ao[ks], b, acc);
            }
            *(floatx4*)&out[(long)(m0 + rt * 16 + nlo) * 64 + otile * 16 + quad * 4] = acc;
        }
    }

    // ---- epilogue 2: hidden finals (seq % 8 == 7), h_l(19) in buf 1 ----
    for (int idx = tid; idx < 3 * 8 * 128; idx += 768) {
        int l2 = idx >> 10, r = idx & 1023, si = r >> 7, k = r & 127;
        int sq = si * 8 + 7;
        long m = m0 + sq;
        out[1048576L + ((long)l2 * 2048 + (m >> 3)) * 128 + k] =
            (float)hA[l2][1][sq][k];
    }
}

extern "C" void kernel_launch(void* const* d_in, const int* in_sizes, int n_in,
                              void* d_out, int out_size, void* d_ws, size_t ws_size,
                              hipStream_t stream)
{
    int ix = 0, ipeA = 1, ipeT = 2, iembW = 3, iembB = 4, iWih0 = 5, iWihR = 6,
        iWhh = 7, ibih = 8, ibhh = 9, ioutW = 10, ioutB = 11;
    int f64 = -1, s64 = -1, f1152 = -1, s1152 = -1;
    for (int i = 0; i < n_in; i++) {
        int s = in_sizes[i];
        if      (s == 655360) ix = i;
        else if (s == 8)      ipeA = i;
        else if (s == 20)     ipeT = i;
        else if (s == 128)    iembW = i;
        else if (s == 24576)  iWih0 = i;
        else if (s == 98304)  iWihR = i;
        else if (s == 147456) iWhh = i;
        else if (s == 8192)   ioutW = i;
        else if (s == 64)     { if (f64 < 0) f64 = i; else s64 = i; }
        else if (s == 1152)   { if (f1152 < 0) f1152 = i; else s1152 = i; }
    }
    if (f64 >= 0)   { iembB = f64;  ioutB = (s64  >= 0 ? s64  : f64); }
    if (f1152 >= 0) { ibih = f1152; ibhh = (s1152 >= 0 ? s1152 : f1152); }

    _Float16* ws = (_Float16*)d_ws;           // 544 frags * 1KB = 557056 B
    float* out = (float*)d_out;

    hipLaunchKernelGGL(prepack_kernel, dim3(544), dim3(64), 0, stream,
                       d_in[iWhh], d_in[iWihR], d_in[iWih0], d_in[ioutW],
                       d_in[ipeT], d_in[ix], ws);
    hipLaunchKernelGGL(rnn_fused, dim3(256), dim3(768), 0, stream,
                       d_in[ix], d_in[ipeA], d_in[ipeT], d_in[iembW], d_in[iembB],
                       d_in[ibih], d_in[ibhh], d_in[ioutB], ws, out);
}

// Round 7
// 474.012 us; speedup vs baseline: 1.1553x; 1.1553x over previous
//
#include <hip/hip_runtime.h>
#include <hip/hip_bf16.h>

// ---------------------------------------------------------------------------
// Fused 3-layer GRU (B*N=16384 seqs, T=20, HS=128) for MI355X / gfx950.
// R20 = R13 (337 us proven) + WEIGHT-ONLY depth-2 software pipeline.
// R19 post-mortem: pipelining weights AND B-frags needed 204 live regs vs
// the (768,3) budget of 168 (512/3) -> scratch spill (FETCH 738 MB, VGPR
// pinned 84). Fix: pipeline ONLY the 3 global weight frags per ks-step
// (+12 regs, peak ~165 <= 168). B frags are LDS (~120cy, lgkmcnt-tracked,
// compiler pipelines them already); the ~200cy L2 weight loads are the
// actual exposed latency (~14 groups/phase -> 2 after this change).
// gh->gi bridge: last gh step prefetches first gi weights.
// Everything else byte-identical to R13: LD=136 (R18: 140 breaks b128
// alignment), rotation kept, clamped activations, scalar emb writes,
// plain __syncthreads (R16: no-drain neutral).
// Canaries: FETCH ~14 MB & VGPR 110-160 = pipeline real; FETCH >= 50 MB =
// spill; VGPR ~84 = compiler sank the prefetch (both -> structural stop).
// ---------------------------------------------------------------------------

typedef _Float16 half8 __attribute__((ext_vector_type(8)));
typedef _Float16 half4 __attribute__((ext_vector_type(4)));
typedef float floatx4 __attribute__((ext_vector_type(4)));

#define MFMA16(a, b, c) __builtin_amdgcn_mfma_f32_16x16x32_f16((a), (b), (c), 0, 0, 0)

static __device__ __forceinline__ float ldin(const void* p, long i, bool f32) {
    return f32 ? ((const float*)p)[i]
               : __bfloat162float(((const __hip_bfloat16*)p)[i]);
}

static __device__ __forceinline__ bool detect_f32(const void* peT, const void* x) {
    const __hip_bfloat16* a = (const __hip_bfloat16*)peT;
    const __hip_bfloat16* b = (const __hip_bfloat16*)x;
    bool weird = false;
    for (int i = 0; i < 20; i++) {
        float v = fabsf(__bfloat162float(a[i]));
        if (!(v == 0.0f || (v > 1e-8f && v < 1e8f))) weird = true;
    }
    for (int i = 0; i < 64; i++) {
        float v = fabsf(__bfloat162float(b[i]));
        if (!(v == 0.0f || (v > 1e-8f && v < 1e8f))) weird = true;
    }
    return weird;
}

static __device__ __forceinline__ float fsigm(float x) {
    x = fminf(fmaxf(x, -60.f), 60.f);
    float e = __builtin_amdgcn_exp2f(-1.442695041f * x);
    return __builtin_amdgcn_rcpf(1.0f + e);
}
static __device__ __forceinline__ float ftanh(float x) {
    x = fminf(fmaxf(x, -30.f), 30.f);
    float e = __builtin_amdgcn_exp2f(2.885390082f * x);  // exp(2x)
    return 1.0f - 2.0f * __builtin_amdgcn_rcpf(1.0f + e);
}

// ws fragment layout (each frag = 512 halfs = 64 lanes x 8): slot order
//   [0,288)   Whh   (3 layers x 96)   frag in layer: (ctile*3+g)*4+ks, ctile 0..7
//   [288,480) WihR  (2 layers x 96)   same formula
//   [480,528) Wih0  (48)              (ctile*3+g)*2+ks   (K=64)
//   [528,544) outW  (16)              otile*4+ks
__global__ __launch_bounds__(64) void prepack_kernel(
    const void* __restrict__ Whh,
    const void* __restrict__ WihR,
    const void* __restrict__ Wih0,
    const void* __restrict__ outW,
    const void* __restrict__ peT,
    const void* __restrict__ x,
    _Float16* __restrict__ ws)
{
    const bool f32 = detect_f32(peT, x);
    int fid  = blockIdx.x;
    int lane = threadIdx.x;
    int nlo = lane & 15, quad = lane >> 4;
    const void* src;
    long base;
    int row, k0, ldk;
    if (fid < 288) {
        int l = fid / 96, r = fid % 96;
        int ks = r & 3, q1 = r >> 2, g = q1 % 3, ctile = q1 / 3;
        row = g * 128 + ctile * 16 + nlo; k0 = ks * 32 + quad * 8; ldk = 128;
        src = Whh; base = (long)l * 384 * 128;
    } else if (fid < 480) {
        int f = fid - 288; int l = f / 96, r = f % 96;
        int ks = r & 3, q1 = r >> 2, g = q1 % 3, ctile = q1 / 3;
        row = g * 128 + ctile * 16 + nlo; k0 = ks * 32 + quad * 8; ldk = 128;
        src = WihR; base = (long)l * 384 * 128;
    } else if (fid < 528) {
        int r = fid - 480;
        int ks = r & 1, q1 = r >> 1, g = q1 % 3, ctile = q1 / 3;
        row = g * 128 + ctile * 16 + nlo; k0 = ks * 32 + quad * 8; ldk = 64;
        src = Wih0; base = 0;
    } else {
        int r = fid - 528; int ks = r & 3, ot = r >> 2;
        row = ot * 16 + nlo; k0 = ks * 32 + quad * 8; ldk = 128;
        src = outW; base = 0;
    }
    _Float16* d = ws + (long)fid * 512 + lane * 8;
#pragma unroll
    for (int j = 0; j < 8; j++)
        d[j] = (_Float16)ldin(src, base + (long)row * ldk + k0 + j, f32);
}

// 12 MFMAs of one ks-step: gates g0->acc[0], g1->acc[1], g2->acc[S2]
// (S2=3 for gh (Nh), S2=2 for gi (Ni))
#define MFMA12(W0, W1, W2, S2, Bq0, Bq1, Bq2, Bq3) \
    acc[0][0] = MFMA16((W0), Bq0, acc[0][0]); \
    acc[0][1] = MFMA16((W0), Bq1, acc[0][1]); \
    acc[0][2] = MFMA16((W0), Bq2, acc[0][2]); \
    acc[0][3] = MFMA16((W0), Bq3, acc[0][3]); \
    acc[1][0] = MFMA16((W1), Bq0, acc[1][0]); \
    acc[1][1] = MFMA16((W1), Bq1, acc[1][1]); \
    acc[1][2] = MFMA16((W1), Bq2, acc[1][2]); \
    acc[1][3] = MFMA16((W1), Bq3, acc[1][3]); \
    acc[S2][0] = MFMA16((W2), Bq0, acc[S2][0]); \
    acc[S2][1] = MFMA16((W2), Bq1, acc[S2][1]); \
    acc[S2][2] = MFMA16((W2), Bq2, acc[S2][2]); \
    acc[S2][3] = MFMA16((W2), Bq3, acc[S2][3]);

__global__ __launch_bounds__(768, 3) void rnn_fused(
    const void* __restrict__ x,
    const void* __restrict__ peA,
    const void* __restrict__ peT,
    const void* __restrict__ embW,
    const void* __restrict__ embB,
    const void* __restrict__ bih,
    const void* __restrict__ bhh,
    const void* __restrict__ outB,
    const _Float16* __restrict__ ws,
    float* __restrict__ out)
{
    __shared__ __align__(16) _Float16 hA[3][2][64][136];
    __shared__ __align__(16) _Float16 eA[2][64][72];
    __shared__ float emb0[64], emb1[64], embb[64];
    __shared__ float biasS[1536];   // [l][R,Z,Ni,Nh][128]

    const bool f32 = detect_f32(peT, x);

    const int tid  = threadIdx.x;
    const int w    = tid >> 6;      // 0..11
    const int lane = tid & 63;
    const int nlo  = lane & 15;
    const int quad = lane >> 4;
    const int qk   = quad * 8;
    const int m0   = blockIdx.x * 64;
    const int rot  = blockIdx.x & 3;          // ks-order rotation (slice skew)
    const int ctr  = (blockIdx.x >> 2) & 1;   // ctile-order rotation

    for (int i = tid; i < 3 * 2 * 64 * 136; i += 768)
        (&hA[0][0][0][0])[i] = (_Float16)0.f;
    if (tid < 64) {
        emb0[tid] = ldin(embW, tid * 2 + 0, f32);
        emb1[tid] = ldin(embW, tid * 2 + 1, f32);
        embb[tid] = ldin(embB, tid, f32);
    }
    for (int idx = tid; idx < 1536; idx += 768) {
        int l = idx >> 9, r = idx & 511, g = r >> 7, c = r & 127;
        float v;
        if      (g == 0) v = ldin(bih, l * 384 + c, f32)       + ldin(bhh, l * 384 + c, f32);
        else if (g == 1) v = ldin(bih, l * 384 + 128 + c, f32) + ldin(bhh, l * 384 + 128 + c, f32);
        else if (g == 2) v = ldin(bih, l * 384 + 256 + c, f32);
        else             v = ldin(bhh, l * 384 + 256 + c, f32);
        biasS[idx] = v;
    }

    const int em = tid >> 2;          // embedding seq (layer-0 waves: tid<256)
    const int ej = (tid & 3) * 16;    // embedding col base
    const float peAg = ldin(peA, ((m0 + em) & 7), f32);

    __syncthreads();

#pragma unroll 1
    for (int s = 0; s < 23; s++) {
        const int l = w >> 2;           // 0..2
        const int W = w & 3;            // quarter: ctiles W*2, W*2+1
        const int t = s - 1 - l;
        if (t >= 0 && t < 20) {
            const int p = (t + 1) & 1;
            const int q = t & 1;
            const int tb = t & 1;
            const int KGI = (l == 0) ? 2 : 4;
            const _Float16* inBase = (l == 0) ? &eA[tb][0][0]
                                              : &hA[l - 1][tb][0][0];
            const int inStride = (l == 0) ? 72 : 136;

#pragma unroll
            for (int ct0 = 0; ct0 < 2; ct0++) {
                const int c8 = W * 2 + ((ct0 + ctr) & 1);   // ctile 0..7
                const int c4 = c8 * 16 + quad * 4;
                // weight bases for this ctile (lane offset folded in)
                const _Float16* fbh = ws + (long)(l * 96 + c8 * 12) * 512 + lane * 8;
                const _Float16* fbi = (l == 0)
                    ? ws + (long)(480 + c8 * 6) * 512 + lane * 8
                    : ws + (long)(288 + (l - 1) * 96 + c8 * 12) * 512 + lane * 8;

                floatx4 acc[4][4];                  // [R,Z,Ni,Nh][rt] - 64 regs
#pragma unroll
                for (int g = 0; g < 4; g++) {
                    floatx4 b = *(const floatx4*)&biasS[(l * 4 + g) * 128 + c4];
#pragma unroll
                    for (int rt = 0; rt < 4; rt++) acc[g][rt] = b;
                }

                // prime: gh weights for first ks (12 regs)
                half8 W0 = *(const half8*)(fbh + (long)(0 * 4 + rot) * 512);
                half8 W1 = *(const half8*)(fbh + (long)(1 * 4 + rot) * 512);
                half8 W2 = *(const half8*)(fbh + (long)(2 * 4 + rot) * 512);

                // ---- gh: 4 ks-steps, weight-only depth-2 pipeline ----
#pragma unroll
                for (int i = 0; i < 4; i++) {
                    const int ks = (rot + i) & 3;
                    half8 N0, N1, N2;           // next step's weights (12 regs)
                    if (i < 3) {
                        const int nk = (rot + i + 1) & 3;
                        N0 = *(const half8*)(fbh + (long)(0 * 4 + nk) * 512);
                        N1 = *(const half8*)(fbh + (long)(1 * 4 + nk) * 512);
                        N2 = *(const half8*)(fbh + (long)(2 * 4 + nk) * 512);
                    } else {                    // bridge: first gi weights
                        const int nk = rot & (KGI - 1);
                        N0 = *(const half8*)(fbi + (long)(0 * KGI + nk) * 512);
                        N1 = *(const half8*)(fbi + (long)(1 * KGI + nk) * 512);
                        N2 = *(const half8*)(fbi + (long)(2 * KGI + nk) * 512);
                    }
                    // B frags just-in-time from LDS (compiler pipelines these)
                    half8 B0 = *(const half8*)&hA[l][p][0 * 16 + nlo][ks * 32 + qk];
                    half8 B1 = *(const half8*)&hA[l][p][1 * 16 + nlo][ks * 32 + qk];
                    half8 B2 = *(const half8*)&hA[l][p][2 * 16 + nlo][ks * 32 + qk];
                    half8 B3 = *(const half8*)&hA[l][p][3 * 16 + nlo][ks * 32 + qk];
                    MFMA12(W0, W1, W2, 3, B0, B1, B2, B3)
                    W0 = N0; W1 = N1; W2 = N2;
                }

                // ---- gi: KGI ks-steps, same pipeline (W holds first gi) ----
                if (l == 0) {
#pragma unroll
                    for (int j = 0; j < 2; j++) {
                        const int ks = (rot + j) & 1;
                        half8 N0, N1, N2;
                        if (j < 1) {
                            const int nk = (rot + j + 1) & 1;
                            N0 = *(const half8*)(fbi + (long)(0 * 2 + nk) * 512);
                            N1 = *(const half8*)(fbi + (long)(1 * 2 + nk) * 512);
                            N2 = *(const half8*)(fbi + (long)(2 * 2 + nk) * 512);
                        }
                        half8 B0 = *(const half8*)(inBase + (0 * 16 + nlo) * 72 + ks * 32 + qk);
                        half8 B1 = *(const half8*)(inBase + (1 * 16 + nlo) * 72 + ks * 32 + qk);
                        half8 B2 = *(const half8*)(inBase + (2 * 16 + nlo) * 72 + ks * 32 + qk);
                        half8 B3 = *(const half8*)(inBase + (3 * 16 + nlo) * 72 + ks * 32 + qk);
                        MFMA12(W0, W1, W2, 2, B0, B1, B2, B3)
                        if (j < 1) { W0 = N0; W1 = N1; W2 = N2; }
                    }
                } else {
#pragma unroll
                    for (int j = 0; j < 4; j++) {
                        const int ks = (rot + j) & 3;
                        half8 N0, N1, N2;
                        if (j < 3) {
                            const int nk = (rot + j + 1) & 3;
                            N0 = *(const half8*)(fbi + (long)(0 * 4 + nk) * 512);
                            N1 = *(const half8*)(fbi + (long)(1 * 4 + nk) * 512);
                            N2 = *(const half8*)(fbi + (long)(2 * 4 + nk) * 512);
                        }
                        half8 B0 = *(const half8*)(inBase + (0 * 16 + nlo) * 136 + ks * 32 + qk);
                        half8 B1 = *(const half8*)(inBase + (1 * 16 + nlo) * 136 + ks * 32 + qk);
                        half8 B2 = *(const half8*)(inBase + (2 * 16 + nlo) * 136 + ks * 32 + qk);
                        half8 B3 = *(const half8*)(inBase + (3 * 16 + nlo) * 136 + ks * 32 + qk);
                        MFMA12(W0, W1, W2, 2, B0, B1, B2, B3)
                        if (j < 3) { W0 = N0; W1 = N1; W2 = N2; }
                    }
                }

                // nonlinearity + f16 writeback (b64) to buf q
#pragma unroll
                for (int rt = 0; rt < 4; rt++) {
                    half4 ho = *(const half4*)&hA[l][p][rt * 16 + nlo][c4];
                    half4 hn;
#pragma unroll
                    for (int rg = 0; rg < 4; rg++) {
                        float r = fsigm(acc[0][rt][rg]);
                        float z = fsigm(acc[1][rt][rg]);
                        float n = ftanh(acc[2][rt][rg] + r * acc[3][rt][rg]);
                        hn[rg] = (_Float16)(n + z * ((float)ho[rg] - n));
                    }
                    *(half4*)&hA[l][q][rt * 16 + nlo][c4] = hn;
                }
            }
        }
        // ---- embedding fused into layer-0 waves: e(t=s) -> eA[s&1] ----
        if (l == 0 && s < 20) {
            float x0 = ldin(x, ((long)(m0 + em) * 20 + s) * 2 + 0, f32);
            float x1 = ldin(x, ((long)(m0 + em) * 20 + s) * 2 + 1, f32);
            float pe = ldin(peT, s, f32) + peAg;
            float xp0 = x0 + pe, xp1 = x1 + pe;
#pragma unroll
            for (int jj = 0; jj < 16; jj++) {
                float e = fmaf(emb0[ej + jj], xp0, fmaf(emb1[ej + jj], xp1, embb[ej + jj]));
                eA[s & 1][em][ej + jj] = (_Float16)fmaxf(e, 0.f);
            }
        }
        __syncthreads();   // single barrier per phase
    }

    // ---- epilogue 1: out = h3(19) @ outW^T + out_b ; h3(19) in buf 1 ----
    if (w < 8) {
        const int otile = w & 3;
        const int rtb   = (w >> 2) * 2;
        half8 Ao[4];
#pragma unroll
        for (int ks = 0; ks < 4; ks++)
            Ao[ks] = *(const half8*)(ws + ((long)(528 + otile * 4 + ks)) * 512 + lane * 8);
        floatx4 ob;
#pragma unroll
        for (int rg = 0; rg < 4; rg++) ob[rg] = ldin(outB, otile * 16 + quad * 4 + rg, f32);
#pragma unroll
        for (int rr = 0; rr < 2; rr++) {
            const int rt = rtb + rr;
            floatx4 acc = ob;
#pragma unroll
            for (int ks = 0; ks < 4; ks++) {
                half8 b = *(const half8*)&hA[2][1][rt * 16 + nlo][ks * 32 + qk];
                acc = MFMA16(Ao[ks], b, acc);
            }
            *(floatx4*)&out[(long)(m0 + rt * 16 + nlo) * 64 + otile * 16 + quad * 4] = acc;
        }
    }

    // ---- epilogue 2: hidden finals (seq % 8 == 7), h_l(19) in buf 1 ----
    for (int idx = tid; idx < 3 * 8 * 128; idx += 768) {
        int l2 = idx >> 10, r = idx & 1023, si = r >> 7, k = r & 127;
        int sq = si * 8 + 7;
        long m = m0 + sq;
        out[1048576L + ((long)l2 * 2048 + (m >> 3)) * 128 + k] =
            (float)hA[l2][1][sq][k];
    }
}

extern "C" void kernel_launch(void* const* d_in, const int* in_sizes, int n_in,
                              void* d_out, int out_size, void* d_ws, size_t ws_size,
                              hipStream_t stream)
{
    int ix = 0, ipeA = 1, ipeT = 2, iembW = 3, iembB = 4, iWih0 = 5, iWihR = 6,
        iWhh = 7, ibih = 8, ibhh = 9, ioutW = 10, ioutB = 11;
    int f64 = -1, s64 = -1, f1152 = -1, s1152 = -1;
    for (int i = 0; i < n_in; i++) {
        int s = in_sizes[i];
        if      (s == 655360) ix = i;
        else if (s == 8)      ipeA = i;
        else if (s == 20)     ipeT = i;
        else if (s == 128)    iembW = i;
        else if (s == 24576)  iWih0 = i;
        else if (s == 98304)  iWihR = i;
        else if (s == 147456) iWhh = i;
        else if (s == 8192)   ioutW = i;
        else if (s == 64)     { if (f64 < 0) f64 = i; else s64 = i; }
        else if (s == 1152)   { if (f1152 < 0) f1152 = i; else s1152 = i; }
    }
    if (f64 >= 0)   { iembB = f64;  ioutB = (s64  >= 0 ? s64  : f64); }
    if (f1152 >= 0) { ibih = f1152; ibhh = (s1152 >= 0 ? s1152 : f1152); }

    _Float16* ws = (_Float16*)d_ws;           // 544 frags * 1KB = 557056 B
    float* out = (float*)d_out;

    hipLaunchKernelGGL(prepack_kernel, dim3(544), dim3(64), 0, stream,
                       d_in[iWhh], d_in[iWihR], d_in[iWih0], d_in[ioutW],
                       d_in[ipeT], d_in[ix], ws);
    hipLaunchKernelGGL(rnn_fused, dim3(256), dim3(768), 0, stream,
                       d_in[ix], d_in[ipeA], d_in[ipeT], d_in[iembW], d_in[iembB],
                       d_in[ibih], d_in[ibhh], d_in[ioutB], ws, out);
}